// Round 7
// baseline (183.740 us; speedup 1.0000x reference)
//
#include <hip/hip_runtime.h>
#include <stdint.h>

#define N_NODES 100000
#define F_DIM   500
#define C_DIM   40
#define H_DIM   256
#define HX_DIM  64
#define O_DIM   320   // H + HX
#define E_NUM   1600000

typedef unsigned short u16;
typedef unsigned int   u32;
typedef __attribute__((ext_vector_type(4))) u16    u16x4;
typedef __attribute__((ext_vector_type(8))) u16    u16x8;
typedef __attribute__((ext_vector_type(4))) float  f32x4;
typedef __attribute__((ext_vector_type(8))) short  bf16x8;  // MFMA A/B frag

__device__ __forceinline__ float bf2f(u16 v) {
  u32 u = ((u32)v) << 16;
  return __builtin_bit_cast(float, u);
}
__device__ __forceinline__ u16 f2bf(float f) {   // round-to-nearest-even
  u32 x = __builtin_bit_cast(u32, f);
  x += 0x7fffu + ((x >> 16) & 1u);
  return (u16)(x >> 16);
}

// ---------------- Kernel 0: train_mask encoding detector ----------------
__global__ __launch_bounds__(256) void k_detect(const u32* __restrict__ tm, int* __restrict__ flag)
{
  __shared__ int s;
  if (threadIdx.x == 0) s = 0;
  __syncthreads();
  int local = 0;
  #pragma unroll
  for (int j = 0; j < 16; ++j) {
    if (tm[j * 256 + threadIdx.x] > 1u) local = 1;
  }
  if (local) s = 1;
  __syncthreads();
  if (threadIdx.x == 0) *flag = s;
}

// ---------------- Kernel 0b: pre-convert W=[fc1_w;xenc_w] to bf16, K-chunked ----------------
// wws[c*10240 + r*32 + s*8 + j] = bf16(W[r][c*32+s*8+j]), zero-padded past K=500.
// This layout makes each wave's MFMA B-FRAGMENT a contiguous, coalesced 16B load:
// frag(n, kc) for lane (l15,lgrp) = wws + kc*10240 + (wc*80+n*16+l15)*32 + lgrp*8.
__global__ __launch_bounds__(256) void k_cvtw(
    const float* __restrict__ fc1w, const float* __restrict__ xencw, u16* __restrict__ wws)
{
  const int g = blockIdx.x * 256 + threadIdx.x;   // 20480 groups
  const int c = g / 1280;
  const int rem = g - c * 1280;
  const int r = rem >> 2;
  const int k0 = c * 32 + (rem & 3) * 8;
  const float* src = (r < H_DIM) ? (fc1w + (long)r * F_DIM)
                                 : (xencw + (long)(r - H_DIM) * F_DIM);
  f32x4 v0 = {0.f, 0.f, 0.f, 0.f}, v1 = v0;
  if (k0 + 4 <= F_DIM) v0 = *(const f32x4*)(src + k0);
  if (k0 + 8 <= F_DIM) v1 = *(const f32x4*)(src + k0 + 4);
  u16x8 o;
  #pragma unroll
  for (int i = 0; i < 4; ++i) { o[i] = f2bf(v0[i]); o[4 + i] = f2bf(v1[i]); }
  *(u16x8*)(wws + (size_t)g * 8) = o;
}

// ---------------- Kernel 1: [h|xe] = relu(x @ W^T + b) ----------------
// v4: B never touches LDS (direct global->reg->MFMA, double-buffered 1-step
// prefetch). A staged in BULK (8 K-chunks = 32 KB) -> 3 barriers total instead
// of 16. LDS 32 KB (epilogue aliases A-space), regs ~160 -> 3 blocks/CU.
#define G_BM 64
#define G_BK 32
#define BN   320

__global__ __launch_bounds__(256, 3) void k_gemm1(
    const float* __restrict__ x, const u16* __restrict__ wws,
    const float* __restrict__ fc1b, const float* __restrict__ xencb,
    u16* __restrict__ hout)
{
  __shared__ char smem[32768];
  u16* sAl   = (u16*)smem;        // 8 chunks x [64 rows x 32 u16] = 32 KB
  u16* sOutB = (u16*)smem;        // epilogue alias: 16 rows x 328 u16 = 10.5 KB

  const int tid  = threadIdx.x;
  const int lane = tid & 63;
  const int wc   = tid >> 6;                // N-strip (80 cols)
  const int l15 = lane & 15, lgrp = lane >> 4;
  const long rowbase = (long)blockIdx.x * G_BM;

  // A staging geometry: thread t -> row ar=t>>2, logical slot as=t&3
  const int ar  = tid >> 2;
  const int as  = tid & 3;
  const int aps = as ^ ((ar >> 1) & 3);     // write-side slot swizzle (validated r5/r6)
  const long arow = rowbase + ar;
  const bool arv = (arow < N_NODES);
  const float* xrow = x + arow * F_DIM;
  const int rslot = (lgrp ^ ((l15 >> 1) & 3)) * 8;   // read-side swizzle

  // B fragment base for this lane (fixed rows across all K-steps)
  const u16* bbase = wws + (wc * 80 + l15) * 32 + lgrp * 8;

  f32x4 acc[4][5];
  #pragma unroll
  for (int m = 0; m < 4; ++m)
    #pragma unroll
    for (int n = 0; n < 5; ++n)
      acc[m][n] = (f32x4){0.f, 0.f, 0.f, 0.f};

#define STAGE_A(hs)                                                            \
  {                                                                            \
    _Pragma("unroll")                                                          \
    for (int c = 0; c < 8; ++c) {                                              \
      const int k0 = ((hs) * 8 + c) * G_BK + as * 8;                           \
      f32x4 v0 = {0.f, 0.f, 0.f, 0.f}, v1 = v0;                                \
      if (arv && k0 + 4 <= F_DIM) v0 = *(const f32x4*)(xrow + k0);             \
      if (arv && k0 + 8 <= F_DIM) v1 = *(const f32x4*)(xrow + k0 + 4);         \
      u16x8 av;                                                                \
      _Pragma("unroll")                                                        \
      for (int i = 0; i < 4; ++i) { av[i] = f2bf(v0[i]); av[4 + i] = f2bf(v1[i]); } \
      *(u16x8*)(sAl + c * 2048 + ar * G_BK + aps * 8) = av;                    \
    }                                                                          \
  }

#define LOAD_B(dst, kc)                                                        \
  {                                                                            \
    const u16* bp = bbase + (kc) * (BN * G_BK);                                \
    _Pragma("unroll")                                                          \
    for (int n = 0; n < 5; ++n) dst[n] = *(const bf16x8*)(bp + n * 512);       \
  }

#define GSTEP(kc, BU, BL)                                                      \
  {                                                                            \
    if ((kc) < 15) LOAD_B(BL, (kc) + 1);                                       \
    const u16* sa = sAl + ((kc) & 7) * 2048;                                   \
    _Pragma("unroll")                                                          \
    for (int m = 0; m < 4; ++m) {                                              \
      const bf16x8 afr = *(const bf16x8*)(sa + (m * 16 + l15) * G_BK + rslot); \
      _Pragma("unroll")                                                        \
      for (int n = 0; n < 5; ++n)                                              \
        acc[m][n] = __builtin_amdgcn_mfma_f32_16x16x32_bf16(afr, BU[n], acc[m][n], 0, 0, 0); \
    }                                                                          \
  }

  bf16x8 bA[5], bB[5];
  LOAD_B(bA, 0);                 // in flight across the staging burst
  STAGE_A(0);
  __syncthreads();

  GSTEP(0,  bA, bB); GSTEP(1,  bB, bA); GSTEP(2,  bA, bB); GSTEP(3,  bB, bA);
  GSTEP(4,  bA, bB); GSTEP(5,  bB, bA); GSTEP(6,  bA, bB); GSTEP(7,  bB, bA);

  __syncthreads();               // all reads of first-half A done
  STAGE_A(1);
  __syncthreads();

  GSTEP(8,  bA, bB); GSTEP(9,  bB, bA); GSTEP(10, bA, bB); GSTEP(11, bB, bA);
  GSTEP(12, bA, bB); GSTEP(13, bB, bA); GSTEP(14, bA, bB); GSTEP(15, bB, bA);

  __syncthreads();               // sAl dead; safe to alias as sOutB

  // ---- epilogue: bias+relu -> LDS 16-row chunks -> coalesced 16B stores ----
  // C/D layout: col=l15, row=lgrp*4+rg within frag; frag row-block = ch.
  float biasv[5];
  #pragma unroll
  for (int n = 0; n < 5; ++n) {
    const int col = wc * 80 + n * 16 + l15;
    biasv[n] = (col < H_DIM) ? fc1b[col] : xencb[col - H_DIM];
  }
  #pragma unroll
  for (int ch = 0; ch < 4; ++ch) {
    #pragma unroll
    for (int n = 0; n < 5; ++n) {
      const int col = wc * 80 + n * 16 + l15;
      #pragma unroll
      for (int rg = 0; rg < 4; ++rg)
        sOutB[(lgrp * 4 + rg) * 328 + col] = f2bf(fmaxf(acc[ch][n][rg] + biasv[n], 0.f));
    }
    __syncthreads();
    #pragma unroll
    for (int it = 0; it < 3; ++it) {
      const int g = it * 256 + tid;           // 640 groups: 16 rows x 40
      if (g < 640) {
        const int r = g / 40, c2 = g - r * 40;
        const long rr = rowbase + ch * 16 + r;
        if (rr < N_NODES)
          *(u16x8*)(hout + rr * O_DIM + c2 * 8) = *(const u16x8*)(sOutB + r * 328 + c2 * 8);
      }
    }
    if (ch < 3) __syncthreads();
  }
#undef STAGE_A
#undef LOAD_B
#undef GSTEP
}

// ---------------- Kernel 2: MFMA row head (validated round 4) ----------------
#define RH_BM 32
#define RH_LD 328

__global__ __launch_bounds__(128) void k_rowhead(
    const u16* __restrict__ hws, const int* __restrict__ y, const void* __restrict__ tmask,
    const float* __restrict__ fc2w, const float* __restrict__ fc2b, const float* __restrict__ pw,
    const int* __restrict__ mask_flag,
    float* __restrict__ out_lp, float* __restrict__ sq_out, float* __restrict__ sk_out)
{
  __shared__ u16 sA[RH_BM * RH_LD];
  __shared__ u16 sB[48 * RH_LD];
  const int tid = threadIdx.x;
  const int lane = tid & 63, wid = tid >> 6;
  const int l15 = lane & 15, lgrp = lane >> 4;
  const long rowbase = (long)blockIdx.x * RH_BM;

  #pragma unroll
  for (int it = 0; it < 10; ++it) {
    const int g = it * 128 + tid;
    const int r = g / 40, c = g - r * 40;
    *(u16x8*)&sA[r * RH_LD + c * 8] =
        *(const u16x8*)(hws + (rowbase + r) * O_DIM + c * 8);
  }
  #pragma unroll
  for (int it = 0; it < 15; ++it) {
    const int g = it * 128 + tid;
    const int r = g / 40, c = g - r * 40;
    const int k0 = c * 8;
    u16x8 v = {0, 0, 0, 0, 0, 0, 0, 0};
    const float* src = nullptr;
    if (r < C_DIM) { if (k0 < H_DIM) src = fc2w + r * H_DIM + k0; }
    else if (r == C_DIM)     { if (k0 >= H_DIM) src = pw + (k0 - H_DIM); }
    else if (r == C_DIM + 1) { if (k0 >= H_DIM) src = pw + HX_DIM + (k0 - H_DIM); }
    if (src) {
      const f32x4 v0 = *(const f32x4*)src;
      const f32x4 v1 = *(const f32x4*)(src + 4);
      #pragma unroll
      for (int i = 0; i < 4; ++i) { v[i] = f2bf(v0[i]); v[4 + i] = f2bf(v1[i]); }
    }
    *(u16x8*)&sB[r * RH_LD + c * 8] = v;
  }
  __syncthreads();

  f32x4 acc[3];
  #pragma unroll
  for (int n = 0; n < 3; ++n) acc[n] = (f32x4){0.f, 0.f, 0.f, 0.f};
  const u16* pa = &sA[(wid * 16 + l15) * RH_LD + lgrp * 8];
  const u16* pb = &sB[l15 * RH_LD + lgrp * 8];
  #pragma unroll
  for (int kc = 0; kc < 10; ++kc) {
    const bf16x8 a = *(const bf16x8*)(pa + kc * 32);
    #pragma unroll
    for (int n = 0; n < 3; ++n) {
      const bf16x8 b = *(const bf16x8*)(pb + n * 16 * RH_LD + kc * 32);
      acc[n] = __builtin_amdgcn_mfma_f32_16x16x32_bf16(a, b, acc[n], 0, 0, 0);
    }
  }

  const int c0 = l15, c1 = 16 + l15, c2 = 32 + l15;
  const bool v2 = (l15 < 8);
  const float b0 = fc2b[c0], b1 = fc2b[c1], b2 = v2 ? fc2b[c2] : 0.f;
  const float wq0 = pw[2 * HX_DIM + c0], wq1 = pw[2 * HX_DIM + c1],
              wq2 = v2 ? pw[2 * HX_DIM + c2] : 0.f;
  const float wk0 = pw[2 * HX_DIM + C_DIM + c0], wk1 = pw[2 * HX_DIM + C_DIM + c1],
              wk2 = v2 ? pw[2 * HX_DIM + C_DIM + c2] : 0.f;
  const bool byte_mask = (*mask_flag != 0);

  #pragma unroll
  for (int rg = 0; rg < 4; ++rg) {
    const long row = rowbase + wid * 16 + lgrp * 4 + rg;
    const float lg0 = acc[0][rg] + b0;
    const float lg1 = acc[1][rg] + b1;
    const float lg2 = acc[2][rg] + b2;
    const float sxq = __shfl(acc[2][rg], (lane & 48) | 8, 64);
    const float sxk = __shfl(acc[2][rg], (lane & 48) | 9, 64);

    float m = fmaxf(lg0, lg1);
    if (v2) m = fmaxf(m, lg2);
    #pragma unroll
    for (int off = 1; off < 16; off <<= 1) m = fmaxf(m, __shfl_xor(m, off, 64));
    const float e0 = __expf(lg0 - m), e1 = __expf(lg1 - m),
                e2 = v2 ? __expf(lg2 - m) : 0.f;
    float s = e0 + e1 + e2;
    #pragma unroll
    for (int off = 1; off < 16; off <<= 1) s += __shfl_xor(s, off, 64);
    const float lse = m + __logf(s);
    const float inv = 1.f / s;

    const int yv = y[row];
    const bool tm = byte_mask ? (((const unsigned char*)tmask)[row] != 0)
                              : (((const int*)tmask)[row] != 0);
    const float p0 = tm ? (c0 == yv ? 1.f : 0.f) : e0 * inv;
    const float p1 = tm ? (c1 == yv ? 1.f : 0.f) : e1 * inv;
    const float p2 = tm ? (c2 == yv ? 1.f : 0.f) : e2 * inv;
    float sq = p0 * wq0 + p1 * wq1 + p2 * wq2;
    float sk = p0 * wk0 + p1 * wk1 + p2 * wk2;
    #pragma unroll
    for (int off = 1; off < 16; off <<= 1) {
      sq += __shfl_xor(sq, off, 64);
      sk += __shfl_xor(sk, off, 64);
    }

    float* lp = out_lp + row * C_DIM;
    lp[c0] = lg0 - lse;
    lp[c1] = lg1 - lse;
    if (v2) lp[c2] = lg2 - lse;
    if (l15 == 0) { sq_out[row] = sq + sxq; sk_out[row] = sk + sxk; }
  }
}

// ---------------- Kernel 3: edge scores ----------------
__global__ __launch_bounds__(256) void k_edges(
    const int* __restrict__ ei, const int* __restrict__ ein,
    const float* __restrict__ sq, const float* __restrict__ sk,
    const float* __restrict__ pb, float* __restrict__ out)
{
  const int e = blockIdx.x * 256 + threadIdx.x;
  if (e >= E_NUM) return;
  const float b = pb[0];
  const int a0 = ei[e],  a1 = ei[E_NUM + e];
  out[e] = sq[a0] + sk[a1] + b;
  const int c0 = ein[e], c1 = ein[E_NUM + e];
  out[E_NUM + e] = sq[c0] + sk[c1] + b;
}

extern "C" void kernel_launch(void* const* d_in, const int* in_sizes, int n_in,
                              void* d_out, int out_size, void* d_ws, size_t ws_size,
                              hipStream_t stream)
{
  const float* x     = (const float*)d_in[0];
  const int*   y     = (const int*)d_in[1];
  const void*  tm    = d_in[2];
  const int*   ei    = (const int*)d_in[3];
  const int*   ein   = (const int*)d_in[4];
  const float* fc1w  = (const float*)d_in[5];
  const float* fc1b  = (const float*)d_in[6];
  const float* fc2w  = (const float*)d_in[7];
  const float* fc2b  = (const float*)d_in[8];
  const float* xencw = (const float*)d_in[9];
  const float* xencb = (const float*)d_in[10];
  const float* pw    = (const float*)d_in[11];
  const float* pb    = (const float*)d_in[12];
  float* out = (float*)d_out;

  // ws: hws (N*320 bf16 = 64 MB) | s_q | s_k | flag | wws (320 KB)
  u16*   hws  = (u16*)d_ws;
  float* sq   = (float*)((char*)d_ws + (size_t)N_NODES * O_DIM * 2);
  float* sk   = sq + N_NODES;
  int*   flag = (int*)(sk + N_NODES);
  u16*   wws  = (u16*)((char*)d_ws + 64800064);

  k_detect<<<1, 256, 0, stream>>>((const u32*)tm, flag);
  k_cvtw  <<<80, 256, 0, stream>>>(fc1w, xencw, wws);
  const int nrb = (N_NODES + G_BM - 1) / G_BM;    // 1563
  k_gemm1 <<<nrb, 256, 0, stream>>>(x, wws, fc1b, xencb, hws);
  k_rowhead<<<N_NODES / RH_BM, 128, 0, stream>>>(
      hws, y, tm, fc2w, fc2b, pw, flag, out + 2 * (size_t)E_NUM, sq, sk);
  k_edges <<<E_NUM / 256, 256, 0, stream>>>(ei, ein, sq, sk, pb, out);
}